// Round 5
// baseline (166.958 us; speedup 1.0000x reference)
//
#include <hip/hip_runtime.h>
#include <math.h>

// NEG loss, R5: XCD E-sliced partial dots.
// V=50000, E=256, B=4096, W=5, S=15. Pair j: contrib = logsig(<in,out_j>)
//   + sum_s logsig(-<in,noise_js>); loss = -sum/B.
// R4 evidence: time invariant at ~51us whether FETCH=163MB or ~0 (warm L3)
// -> bound by L2-miss service (latency x limited outstanding), not HBM BW.
// R5: XCD x only touches a 128B column-slice [x*32,x*32+32) of every row
// (blockIdx%8 -> XCD round-robin heuristic; correctness independent of it).
// Per-XCD footprint 58MB -> 8.5MB -> L2 hits replace L3 round-trips.
// Partial dots (nonlinear logsig needs full 256-dot) round-trip via d_ws:
// 8 x ND floats (10.5MB, coalesced), combined in kernel 2.

#define EDIM 256
#define SNEG 15
#define NSLICE 8
#define SLICE_COLS 32   // 32 cols * 4B = 128B = L2-line aligned slice

__device__ __forceinline__ float log_sigmoid_fast(float x) {
    // min(x,0) - log(1+exp(-|x|)); log arg in (1,2] -> accurate, branch-free
    return fminf(x, 0.0f) - __logf(1.0f + __expf(-fabsf(x)));
}

__global__ void zero_acc_kernel(double* acc) { *acc = 0.0; }

// ---- kernel 1: per-slice partial dots --------------------------------------
// block b: slice = b & 7 (XCD affinity heuristic), stripe = b >> 3.
// wave handles index i (W-fused: pairs i, i+B, ..., i+4B share vin).
// lane: g = lane>>3 selects dot-in-round (8 concurrent dots), t = lane&7
// owns cols col0..col0+3. One load inst = 8 rows x 128B = 1KB, fully used.
__global__ __launch_bounds__(256, 8) void slice_dots_kernel(
    const float* __restrict__ in_w,     // [V,E]
    const float* __restrict__ out_w,    // [V,E]
    const int* __restrict__ in_lab,     // [B]
    const int* __restrict__ out_lab,    // [B*W]
    const int* __restrict__ noise_lab,  // [B*W,S]
    float* __restrict__ partials,       // [NSLICE][ND]
    int B, int BW, int ND)
{
    const int wave = threadIdx.x >> 6;
    const int lane = threadIdx.x & 63;
    const int g = lane >> 3;   // which dot within a round (0..7)
    const int t = lane & 7;    // col-chunk within slice (0..7)
    const int s = blockIdx.x & (NSLICE - 1);
    const int stripe = blockIdx.x >> 3;
    const int nstripe = gridDim.x >> 3;
    const int W = BW / B;

    float* pslice = partials + (size_t)s * ND;
    const int col0 = s * SLICE_COLS + t * 4;

    for (int i = stripe * 4 + wave; i < B; i += nstripe * 4) {
        const int in_row = in_lab[i];
        const float4 vi = *(const float4*)(in_w + (size_t)in_row * EDIM + col0);

        for (int m = 0; m < W; ++m) {
            const int j = i + m * B;            // j % B == i (tile semantics)
            const int out_row = out_lab[j];
            const int* nl = noise_lab + (size_t)j * SNEG;

            // two rounds of 8 dots; issue both row loads before reducing
            const int row0 = (g == 0) ? out_row : nl[g - 1];   // d = g
            const int row1 = nl[7 + g];                        // d = 8+g
            const float4 v0 = *(const float4*)(out_w + (size_t)row0 * EDIM + col0);
            const float4 v1 = *(const float4*)(out_w + (size_t)row1 * EDIM + col0);

            float p0 = vi.x * v0.x + vi.y * v0.y + vi.z * v0.z + vi.w * v0.w;
            float p1 = vi.x * v1.x + vi.y * v1.y + vi.z * v1.z + vi.w * v1.w;
            p0 += __shfl_xor(p0, 1, 64);
            p1 += __shfl_xor(p1, 1, 64);
            p0 += __shfl_xor(p0, 2, 64);
            p1 += __shfl_xor(p1, 2, 64);
            p0 += __shfl_xor(p0, 4, 64);
            p1 += __shfl_xor(p1, 4, 64);

            if (t == 0) {
                const size_t base = (size_t)j * 16;
                pslice[base + g] = p0;          // d = 0..7 (d==0 is positive)
                pslice[base + 8 + g] = p1;      // d = 8..15
            }
        }
    }
}

// ---- kernel 2: combine 8 slice-partials, logsig, reduce --------------------
__global__ __launch_bounds__(256) void combine_kernel(
    const float* __restrict__ partials, double* __restrict__ acc, int ND)
{
    __shared__ float wsum[4];
    const int n = blockIdx.x * 256 + threadIdx.x;
    float c = 0.0f;
    if (n < ND) {
        float ssum = 0.0f;
#pragma unroll
        for (int s = 0; s < NSLICE; ++s) ssum += partials[(size_t)s * ND + n];
        const float x = ((n & 15) == 0) ? ssum : -ssum;  // d==0: positive pair
        c = log_sigmoid_fast(x);
    }
    c += __shfl_xor(c, 1, 64);
    c += __shfl_xor(c, 2, 64);
    c += __shfl_xor(c, 4, 64);
    c += __shfl_xor(c, 8, 64);
    c += __shfl_xor(c, 16, 64);
    c += __shfl_xor(c, 32, 64);
    if ((threadIdx.x & 63) == 0) wsum[threadIdx.x >> 6] = c;
    __syncthreads();
    if (threadIdx.x == 0)
        atomicAdd(acc, (double)(wsum[0] + wsum[1] + wsum[2] + wsum[3]));
}

__global__ void finalize_kernel(const double* acc, float* out, double invB) {
    *out = (float)(-(*acc) * invB);
}

// ---- fallback (R4 structure) if ws_size can't hold the partials ------------
__device__ __forceinline__ float dot4(float4 a, float4 b) {
    return a.x * b.x + a.y * b.y + a.z * b.z + a.w * b.w;
}

__global__ __launch_bounds__(256, 5) void neg_loss_fallback(
    const float* __restrict__ in_w, const float* __restrict__ out_w,
    const int* __restrict__ in_lab, const int* __restrict__ out_lab,
    const int* __restrict__ noise_lab, float* __restrict__ partials,
    int B, int BW)
{
    __shared__ float wave_sums[4];
    const int wave = threadIdx.x >> 6;
    const int lane = threadIdx.x & 63;
    const int q = lane >> 4;
    const int t = lane & 15;
    const int gw = blockIdx.x * 4 + wave;
    const int TW = gridDim.x * 4;

    float c = 0.0f;
    for (int j = gw; j < BW; j += TW) {
        const int in_row = in_lab[j % B];
        const int out_row = out_lab[j];
        const int* nl = noise_lab + (size_t)j * SNEG;
        const float* vin_base = in_w + (size_t)in_row * EDIM + t * 4;
        float4 vi[4];
#pragma unroll
        for (int k = 0; k < 4; ++k) vi[k] = *(const float4*)(vin_base + k * 64);
#pragma unroll
        for (int r = 0; r < 4; ++r) {
            const int d = r * 4 + q;
            const int row = (d == 0) ? out_row : nl[d - 1];
            const float* rb = out_w + (size_t)row * EDIM + t * 4;
            float s = dot4(vi[0], *(const float4*)(rb + 0)) +
                      dot4(vi[1], *(const float4*)(rb + 64)) +
                      dot4(vi[2], *(const float4*)(rb + 128)) +
                      dot4(vi[3], *(const float4*)(rb + 192));
            s += __shfl_xor(s, 1, 64);
            s += __shfl_xor(s, 2, 64);
            s += __shfl_xor(s, 4, 64);
            s += __shfl_xor(s, 8, 64);
            c += log_sigmoid_fast((d == 0) ? s : -s);
        }
    }
    c += __shfl_xor(c, 16, 64);
    c += __shfl_xor(c, 32, 64);
    if (lane == 0) wave_sums[wave] = c;
    __syncthreads();
    if (threadIdx.x == 0)
        partials[blockIdx.x] = wave_sums[0] + wave_sums[1] + wave_sums[2] + wave_sums[3];
}

__global__ __launch_bounds__(256) void reduce_fallback(
    const float* __restrict__ partials, float* __restrict__ out, int n, double invB)
{
    __shared__ double wsum[4];
    double t = 0.0;
    for (int i = threadIdx.x; i < n; i += 256) t += (double)partials[i];
    t += __shfl_xor(t, 32, 64);
    t += __shfl_xor(t, 16, 64);
    t += __shfl_xor(t, 8, 64);
    t += __shfl_xor(t, 4, 64);
    t += __shfl_xor(t, 2, 64);
    t += __shfl_xor(t, 1, 64);
    if ((threadIdx.x & 63) == 0) wsum[threadIdx.x >> 6] = t;
    __syncthreads();
    if (threadIdx.x == 0)
        *out = (float)(-(wsum[0] + wsum[1] + wsum[2] + wsum[3]) * invB);
}

extern "C" void kernel_launch(void* const* d_in, const int* in_sizes, int n_in,
                              void* d_out, int out_size, void* d_ws, size_t ws_size,
                              hipStream_t stream) {
    const float* in_w      = (const float*)d_in[0];
    const float* out_w     = (const float*)d_in[1];
    const int*   in_lab    = (const int*)d_in[2];
    const int*   out_lab   = (const int*)d_in[3];
    const int*   noise_lab = (const int*)d_in[4];

    const int B  = in_sizes[2];        // 4096
    const int BW = in_sizes[3];        // 20480
    const int ND = BW * 16;            // 327680 dots
    const size_t partial_bytes = (size_t)NSLICE * ND * sizeof(float);

    float* out = (float*)d_out;

    if (ws_size >= partial_bytes + 16) {
        float* partials = (float*)d_ws;
        double* acc = (double*)((char*)d_ws + partial_bytes);

        zero_acc_kernel<<<1, 1, 0, stream>>>(acc);
        // 2048 blocks = 256 stripes x 8 slices; 32 waves/CU fully resident
        slice_dots_kernel<<<2048, 256, 0, stream>>>(
            in_w, out_w, in_lab, out_lab, noise_lab, partials, B, BW, ND);
        combine_kernel<<<(ND + 255) / 256, 256, 0, stream>>>(partials, acc, ND);
        finalize_kernel<<<1, 1, 0, stream>>>(acc, out, 1.0 / (double)B);
    } else {
        float* partials = (float*)d_ws;
        const int blocks = 1280;
        neg_loss_fallback<<<blocks, 256, 0, stream>>>(
            in_w, out_w, in_lab, out_lab, noise_lab, partials, B, BW);
        reduce_fallback<<<1, 256, 0, stream>>>(partials, out, blocks, 1.0 / (double)B);
    }
}

// Round 6
// 152.808 us; speedup vs baseline: 1.0926x; 1.0926x over previous
//
#include <hip/hip_runtime.h>
#include <math.h>

// NEG loss, R6: W-fused, depth-3 software-pipelined gather.
// V=50000, E=256, B=4096, W=5, S=15. Pair j: contrib = logsig(<in,out_j>)
//   + sum_s logsig(-<in,noise_js>); loss = -sum/B.
//
// Evidence: ~51us invariant to HBM-vs-L3 source (R4 warm replay), to
// occupancy 33->70% (R4/R5), and to L2 footprint halving (R5). Surviving
// theory: per-wave MLP stuck at ~2 row-loads in flight (compiler
// re-serialized R3's attempt; VGPR stayed 52). R6 forces MLP structurally:
//  - wave owns one i (W-fusion: vin loaded once for all 20 rounds)
//  - 16 dots/window x 5 windows = 20 rounds of 4 quarter-wave dots
//  - depth-3 register pipeline: round k consumes buf[k%3], then reloads it
//    with round k+3's rows; sched_barrier(0) at each round boundary stops
//    the scheduler from sinking loads back to their uses
//  - __launch_bounds__(256,4): 128-VGPR budget so the pipeline fits
// Discriminator: VGPR ~100 + unchanged time => request-rate ceiling, go dedup.

#define EDIM 256
#define SNEG 15

__device__ __forceinline__ float dot4(float4 a, float4 b) {
    return a.x * b.x + a.y * b.y + a.z * b.z + a.w * b.w;
}

__device__ __forceinline__ float log_sigmoid_fast(float x) {
    // min(x,0) - log(1+exp(-|x|)); log arg in (1,2] -> accurate, branch-free
    return fminf(x, 0.0f) - __logf(1.0f + __expf(-fabsf(x)));
}

// ---- fast path: W == 5 (20 rounds hardcoded) -------------------------------
__global__ __launch_bounds__(256, 4) void neg_loss_w5_kernel(
    const float* __restrict__ in_w,     // [V,E]
    const float* __restrict__ out_w,    // [V,E]
    const int* __restrict__ in_lab,     // [B]
    const int* __restrict__ out_lab,    // [B*W]
    const int* __restrict__ noise_lab,  // [B*W,S]
    float* __restrict__ partials,       // [gridDim.x]
    int B)
{
    __shared__ float wave_sums[4];
    const int wave = threadIdx.x >> 6;
    const int lane = threadIdx.x & 63;
    const int q    = lane >> 4;   // quarter-wave: which dot of the round
    const int t    = lane & 15;   // col-chunk: cols t*4 + chunk*64

    const int i = blockIdx.x * 4 + wave;
    float c = 0.0f;

    if (i < B) {
        const int in_row = in_lab[i];
        const float* vb = in_w + (size_t)in_row * EDIM + t * 4;
        const float4 vi0 = *(const float4*)(vb + 0);
        const float4 vi1 = *(const float4*)(vb + 64);
        const float4 vi2 = *(const float4*)(vb + 128);
        const float4 vi3 = *(const float4*)(vb + 192);

        // preload all 20 row indices (round k: m=k>>2, r=k&3, d=r*4+q)
        int rows[20];
#pragma unroll
        for (int k = 0; k < 20; ++k) {
            const int m = k >> 2;
            const int r = k & 3;
            const int d = r * 4 + q;
            const int j = i + m * B;          // j % B == i (tile semantics)
            rows[k] = (d == 0) ? out_lab[j]
                               : noise_lab[(size_t)j * SNEG + (d - 1)];
        }

        // depth-3 pipeline: prime 3 rounds
        float4 buf[3][4];
#pragma unroll
        for (int p = 0; p < 3; ++p) {
            const float* rb = out_w + (size_t)rows[p] * EDIM + t * 4;
            buf[p][0] = *(const float4*)(rb + 0);
            buf[p][1] = *(const float4*)(rb + 64);
            buf[p][2] = *(const float4*)(rb + 128);
            buf[p][3] = *(const float4*)(rb + 192);
        }
        __builtin_amdgcn_sched_barrier(0);

#pragma unroll
        for (int k = 0; k < 20; ++k) {
            const int p = k % 3;
            // consume round k
            float s = dot4(vi0, buf[p][0]) + dot4(vi1, buf[p][1]) +
                      dot4(vi2, buf[p][2]) + dot4(vi3, buf[p][3]);
            // refill this buffer with round k+3 (issues while k+1,k+2 compute)
            if (k + 3 < 20) {
                const float* rb = out_w + (size_t)rows[k + 3] * EDIM + t * 4;
                buf[p][0] = *(const float4*)(rb + 0);
                buf[p][1] = *(const float4*)(rb + 64);
                buf[p][2] = *(const float4*)(rb + 128);
                buf[p][3] = *(const float4*)(rb + 192);
            }
            // quarter-wave reduce (xor over t bits)
            s += __shfl_xor(s, 1, 64);
            s += __shfl_xor(s, 2, 64);
            s += __shfl_xor(s, 4, 64);
            s += __shfl_xor(s, 8, 64);
            const bool pos = ((k & 3) == 0) && (q == 0);   // d == 0
            c += log_sigmoid_fast(pos ? s : -s);
            __builtin_amdgcn_sched_barrier(0);
        }

        c += __shfl_xor(c, 16, 64);
        c += __shfl_xor(c, 32, 64);
    }

    if (lane == 0) wave_sums[wave] = c;
    __syncthreads();
    if (threadIdx.x == 0) {
        partials[blockIdx.x] =
            wave_sums[0] + wave_sums[1] + wave_sums[2] + wave_sums[3];
    }
}

// ---- generic fallback (R4 structure, known-good) ---------------------------
__global__ __launch_bounds__(256, 5) void neg_loss_fallback(
    const float* __restrict__ in_w, const float* __restrict__ out_w,
    const int* __restrict__ in_lab, const int* __restrict__ out_lab,
    const int* __restrict__ noise_lab, float* __restrict__ partials,
    int B, int BW)
{
    __shared__ float wave_sums[4];
    const int wave = threadIdx.x >> 6;
    const int lane = threadIdx.x & 63;
    const int q = lane >> 4;
    const int t = lane & 15;
    const int gw = blockIdx.x * 4 + wave;
    const int TW = gridDim.x * 4;

    float c = 0.0f;
    for (int j = gw; j < BW; j += TW) {
        const int in_row = in_lab[j % B];
        const int out_row = out_lab[j];
        const int* nl = noise_lab + (size_t)j * SNEG;
        const float* vin_base = in_w + (size_t)in_row * EDIM + t * 4;
        float4 vi[4];
#pragma unroll
        for (int k = 0; k < 4; ++k) vi[k] = *(const float4*)(vin_base + k * 64);
#pragma unroll
        for (int r = 0; r < 4; ++r) {
            const int d = r * 4 + q;
            const int row = (d == 0) ? out_row : nl[d - 1];
            const float* rb = out_w + (size_t)row * EDIM + t * 4;
            float s = dot4(vi[0], *(const float4*)(rb + 0)) +
                      dot4(vi[1], *(const float4*)(rb + 64)) +
                      dot4(vi[2], *(const float4*)(rb + 128)) +
                      dot4(vi[3], *(const float4*)(rb + 192));
            s += __shfl_xor(s, 1, 64);
            s += __shfl_xor(s, 2, 64);
            s += __shfl_xor(s, 4, 64);
            s += __shfl_xor(s, 8, 64);
            c += log_sigmoid_fast((d == 0) ? s : -s);
        }
    }
    c += __shfl_xor(c, 16, 64);
    c += __shfl_xor(c, 32, 64);
    if (lane == 0) wave_sums[wave] = c;
    __syncthreads();
    if (threadIdx.x == 0)
        partials[blockIdx.x] = wave_sums[0] + wave_sums[1] + wave_sums[2] + wave_sums[3];
}

__global__ __launch_bounds__(256) void reduce_kernel(
    const float* __restrict__ partials, float* __restrict__ out,
    int n, double invB)
{
    __shared__ double wsum[4];
    double t = 0.0;
    for (int i = threadIdx.x; i < n; i += 256) t += (double)partials[i];
    t += __shfl_xor(t, 32, 64);
    t += __shfl_xor(t, 16, 64);
    t += __shfl_xor(t, 8, 64);
    t += __shfl_xor(t, 4, 64);
    t += __shfl_xor(t, 2, 64);
    t += __shfl_xor(t, 1, 64);
    if ((threadIdx.x & 63) == 0) wsum[threadIdx.x >> 6] = t;
    __syncthreads();
    if (threadIdx.x == 0) {
        double s = wsum[0] + wsum[1] + wsum[2] + wsum[3];
        *out = (float)(-s * invB);
    }
}

extern "C" void kernel_launch(void* const* d_in, const int* in_sizes, int n_in,
                              void* d_out, int out_size, void* d_ws, size_t ws_size,
                              hipStream_t stream) {
    const float* in_w      = (const float*)d_in[0];
    const float* out_w     = (const float*)d_in[1];
    const int*   in_lab    = (const int*)d_in[2];
    const int*   out_lab   = (const int*)d_in[3];
    const int*   noise_lab = (const int*)d_in[4];

    const int B  = in_sizes[2];   // 4096
    const int BW = in_sizes[3];   // 20480

    float* partials = (float*)d_ws;
    float* out      = (float*)d_out;

    if (BW == 5 * B) {
        const int blocks = (B + 3) / 4;   // one wave per i, exact balance
        neg_loss_w5_kernel<<<blocks, 256, 0, stream>>>(
            in_w, out_w, in_lab, out_lab, noise_lab, partials, B);
        reduce_kernel<<<1, 256, 0, stream>>>(partials, out, blocks,
                                             1.0 / (double)B);
    } else {
        const int blocks = 1280;
        neg_loss_fallback<<<blocks, 256, 0, stream>>>(
            in_w, out_w, in_lab, out_lab, noise_lab, partials, B, BW);
        reduce_kernel<<<1, 256, 0, stream>>>(partials, out, blocks,
                                             1.0 / (double)B);
    }
}

// Round 8
// 133.037 us; speedup vs baseline: 1.2550x; 1.1486x over previous
//
#include <hip/hip_runtime.h>
#include <math.h>

// NEG loss, R8 (= R7 with compile fix): fp8-quantized out-table gather.
// V=50000, E=256, B=4096, W=5, S=15. loss = -(sum_j logsig(<in,out_j>)
//   + sum_js logsig(-<in,noise_js>))/B.
//
// Evidence R2-R6: every structure (occ 3..70%, VGPR 20..64, footprint sliced,
// warm L3 vs cold HBM, forced MLP) delivers ~335MB of gathered rows in ~48us
// = 7.0 TB/s = 11.4 B/cyc/CU -> CU-side delivered-gather-bytes wall.
// Only remaining lever: fewer gathered bytes. Tolerance is 3.6 abs on ~450
// -> quantize out_w to fp8 e4m3 (HW cvt) once per launch: rows 1KB -> 256B,
// gathered bytes 335 -> ~90MB. Dot error ~0.1 abs, final error ~0.3 << 3.6.
// Quarter-wave reads a WHOLE fp8 row per instr (lane t: uint4 = els t*16..+15).

#define EDIM 256
#define SNEG 15

typedef float v2f __attribute__((ext_vector_type(2)));

__device__ __forceinline__ float log_sigmoid_fast(float x) {
    // min(x,0) - log(1+exp(-|x|)); log arg in (1,2] -> accurate, branch-free
    return fminf(x, 0.0f) - __logf(1.0f + __expf(-fabsf(x)));
}

__device__ __forceinline__ float dot4(float4 a, float4 b) {
    return a.x * b.x + a.y * b.y + a.z * b.z + a.w * b.w;
}

// ---- kernel A: fp32 -> fp8 e4m3 table (256B/row), rebuilt every launch -----
__global__ __launch_bounds__(256) void cvt_fp8_kernel(
    const float* __restrict__ w, unsigned int* __restrict__ tab, int n4)
{
    const int idx = blockIdx.x * 256 + threadIdx.x;
    if (idx < n4) {
        const float4 f = ((const float4*)w)[idx];
        int p = __builtin_amdgcn_cvt_pk_fp8_f32(f.x, f.y, 0, false);
        p = __builtin_amdgcn_cvt_pk_fp8_f32(f.z, f.w, p, true);
        tab[idx] = (unsigned int)p;
    }
}

// ---- kernel B: W-fused gather over fp8 rows --------------------------------
// wave owns one i; 80 dots = 20 rounds x 4 quarter-wave dots. Lane (q,t):
// quarter q handles dot d = (k&3)*4+q of window m = k>>2; lane t reads
// uint4 = 16 fp8 els at row*256 + t*16 (one wave-instr = 4 full rows = 1KB).
// vin stays fp32 (in-side is only 4MB total, not worth quantizing).
__global__ __launch_bounds__(256, 6) void neg_loss_fp8_kernel(
    const float* __restrict__ in_w,       // [V,E] fp32
    const unsigned int* __restrict__ tab, // [V,E/4] fp8x4
    const int* __restrict__ in_lab,       // [B]
    const int* __restrict__ out_lab,      // [B*W]
    const int* __restrict__ noise_lab,    // [B*W,S]
    float* __restrict__ partials,         // [gridDim.x]
    int B)
{
    __shared__ float wave_sums[4];
    const int wave = threadIdx.x >> 6;
    const int lane = threadIdx.x & 63;
    const int q    = lane >> 4;   // quarter: which dot of the round
    const int t    = lane & 15;   // 16-el chunk within the row

    const int i = blockIdx.x * 4 + wave;
    float c = 0.0f;

    if (i < B) {
        const int in_row = in_lab[i];
        // vin slice for lane t: els [t*16, t*16+16) as 4 float4
        const float* vb = in_w + (size_t)in_row * EDIM + t * 16;
        const float4 vi0 = *(const float4*)(vb + 0);
        const float4 vi1 = *(const float4*)(vb + 4);
        const float4 vi2 = *(const float4*)(vb + 8);
        const float4 vi3 = *(const float4*)(vb + 12);

        // preload the 20 row indices this quarter needs
        int rows[20];
#pragma unroll
        for (int k = 0; k < 20; ++k) {
            const int m = k >> 2;
            const int d = (k & 3) * 4 + q;
            const int j = i + m * B;          // j % B == i (tile semantics)
            rows[k] = (d == 0) ? out_lab[j]
                               : noise_lab[(size_t)j * SNEG + (d - 1)];
        }

        // depth-3 pipeline over 20 single-instr row loads
        uint4 buf[3];
#pragma unroll
        for (int p = 0; p < 3; ++p)
            buf[p] = *(const uint4*)((const char*)tab + (size_t)rows[p] * EDIM + t * 16);
        __builtin_amdgcn_sched_barrier(0);

#pragma unroll
        for (int k = 0; k < 20; ++k) {
            const int p = k % 3;
            const uint4 w = buf[p];
            if (k + 3 < 20)
                buf[p] = *(const uint4*)((const char*)tab +
                                         (size_t)rows[k + 3] * EDIM + t * 16);
            // decode 16 fp8 els and dot against fp32 vin
            float s;
            {
                v2f a = __builtin_amdgcn_cvt_pk_f32_fp8(w.x, false);
                v2f b = __builtin_amdgcn_cvt_pk_f32_fp8(w.x, true);
                s  = a[0] * vi0.x + a[1] * vi0.y + b[0] * vi0.z + b[1] * vi0.w;
            }
            {
                v2f a = __builtin_amdgcn_cvt_pk_f32_fp8(w.y, false);
                v2f b = __builtin_amdgcn_cvt_pk_f32_fp8(w.y, true);
                s += a[0] * vi1.x + a[1] * vi1.y + b[0] * vi1.z + b[1] * vi1.w;
            }
            {
                v2f a = __builtin_amdgcn_cvt_pk_f32_fp8(w.z, false);
                v2f b = __builtin_amdgcn_cvt_pk_f32_fp8(w.z, true);
                s += a[0] * vi2.x + a[1] * vi2.y + b[0] * vi2.z + b[1] * vi2.w;
            }
            {
                v2f a = __builtin_amdgcn_cvt_pk_f32_fp8(w.w, false);
                v2f b = __builtin_amdgcn_cvt_pk_f32_fp8(w.w, true);
                s += a[0] * vi3.x + a[1] * vi3.y + b[0] * vi3.z + b[1] * vi3.w;
            }
            // reduce over the 16 lanes of this quarter
            s += __shfl_xor(s, 1, 64);
            s += __shfl_xor(s, 2, 64);
            s += __shfl_xor(s, 4, 64);
            s += __shfl_xor(s, 8, 64);
            const bool pos = ((k & 3) == 0) && (q == 0);   // d == 0
            if (t == 0) c += log_sigmoid_fast(pos ? s : -s);
            __builtin_amdgcn_sched_barrier(0);
        }

        // c nonzero only on t==0 lanes (0,16,32,48): xor-sum gives total
        c += __shfl_xor(c, 16, 64);
        c += __shfl_xor(c, 32, 64);
    }

    if (lane == 0) wave_sums[wave] = c;
    __syncthreads();
    if (threadIdx.x == 0) {
        partials[blockIdx.x] =
            wave_sums[0] + wave_sums[1] + wave_sums[2] + wave_sums[3];
    }
}

// ---- generic fallback (R4/R6 structure, known-good, fp32) ------------------
__global__ __launch_bounds__(256, 5) void neg_loss_fallback(
    const float* __restrict__ in_w, const float* __restrict__ out_w,
    const int* __restrict__ in_lab, const int* __restrict__ out_lab,
    const int* __restrict__ noise_lab, float* __restrict__ partials,
    int B, int BW)
{
    __shared__ float wave_sums[4];
    const int wave = threadIdx.x >> 6;
    const int lane = threadIdx.x & 63;
    const int q = lane >> 4;
    const int t = lane & 15;
    const int gw = blockIdx.x * 4 + wave;
    const int TW = gridDim.x * 4;

    float c = 0.0f;
    for (int j = gw; j < BW; j += TW) {
        const int in_row = in_lab[j % B];
        const int out_row = out_lab[j];
        const int* nl = noise_lab + (size_t)j * SNEG;
        const float* vin_base = in_w + (size_t)in_row * EDIM + t * 4;
        float4 vi[4];
#pragma unroll
        for (int k = 0; k < 4; ++k) vi[k] = *(const float4*)(vin_base + k * 64);
#pragma unroll
        for (int r = 0; r < 4; ++r) {
            const int d = r * 4 + q;
            const int row = (d == 0) ? out_row : nl[d - 1];
            const float* rb = out_w + (size_t)row * EDIM + t * 4;
            float s = dot4(vi[0], *(const float4*)(rb + 0)) +
                      dot4(vi[1], *(const float4*)(rb + 64)) +
                      dot4(vi[2], *(const float4*)(rb + 128)) +
                      dot4(vi[3], *(const float4*)(rb + 192));
            s += __shfl_xor(s, 1, 64);
            s += __shfl_xor(s, 2, 64);
            s += __shfl_xor(s, 4, 64);
            s += __shfl_xor(s, 8, 64);
            c += log_sigmoid_fast((d == 0) ? s : -s);
        }
    }
    c += __shfl_xor(c, 16, 64);
    c += __shfl_xor(c, 32, 64);
    if (lane == 0) wave_sums[wave] = c;
    __syncthreads();
    if (threadIdx.x == 0)
        partials[blockIdx.x] = wave_sums[0] + wave_sums[1] + wave_sums[2] + wave_sums[3];
}

__global__ __launch_bounds__(256) void reduce_kernel(
    const float* __restrict__ partials, float* __restrict__ out,
    int n, double invB)
{
    __shared__ double wsum[4];
    double t = 0.0;
    for (int i = threadIdx.x; i < n; i += 256) t += (double)partials[i];
    t += __shfl_xor(t, 32, 64);
    t += __shfl_xor(t, 16, 64);
    t += __shfl_xor(t, 8, 64);
    t += __shfl_xor(t, 4, 64);
    t += __shfl_xor(t, 2, 64);
    t += __shfl_xor(t, 1, 64);
    if ((threadIdx.x & 63) == 0) wsum[threadIdx.x >> 6] = t;
    __syncthreads();
    if (threadIdx.x == 0) {
        double s = wsum[0] + wsum[1] + wsum[2] + wsum[3];
        *out = (float)(-s * invB);
    }
}

extern "C" void kernel_launch(void* const* d_in, const int* in_sizes, int n_in,
                              void* d_out, int out_size, void* d_ws, size_t ws_size,
                              hipStream_t stream) {
    const float* in_w      = (const float*)d_in[0];
    const float* out_w     = (const float*)d_in[1];
    const int*   in_lab    = (const int*)d_in[2];
    const int*   out_lab   = (const int*)d_in[3];
    const int*   noise_lab = (const int*)d_in[4];

    const int B    = in_sizes[2];      // 4096
    const int BW   = in_sizes[3];      // 20480
    const int n_ow = in_sizes[1];      // V*E = 12.8M
    const int n4   = n_ow / 4;

    float* out = (float*)d_out;

    const size_t tab_bytes = (size_t)n_ow;            // 1B per element
    const int gblocks = (B + 3) / 4;                  // 1024
    const size_t need = tab_bytes + (size_t)gblocks * sizeof(float) + 256;

    if (BW == 5 * B && ws_size >= need) {
        unsigned int* tab = (unsigned int*)d_ws;
        float* partials = (float*)((char*)d_ws + tab_bytes);

        cvt_fp8_kernel<<<(n4 + 255) / 256, 256, 0, stream>>>(out_w, tab, n4);
        neg_loss_fp8_kernel<<<gblocks, 256, 0, stream>>>(
            in_w, tab, in_lab, out_lab, noise_lab, partials, B);
        reduce_kernel<<<1, 256, 0, stream>>>(partials, out, gblocks,
                                             1.0 / (double)B);
    } else {
        float* partials = (float*)d_ws;
        const int blocks = 1280;
        neg_loss_fallback<<<blocks, 256, 0, stream>>>(
            in_w, out_w, in_lab, out_lab, noise_lab, partials, B, BW);
        reduce_kernel<<<1, 256, 0, stream>>>(partials, out, blocks,
                                             1.0 / (double)B);
    }
}